// Round 10
// baseline (43.403 us; speedup 1.0000x reference)
//
#include <hip/hip_runtime.h>
#include <cstdint>

#define NB 32
#define NROIS 8192
#define NGT 128
#define NALL (NROIS + NGT)   // 8320
#define NHALF (NALL / 2)     // 4160
#define NSAMP 512
#define KPOS 128
#define KNEG 384
#define BCAP 1024
#define TS 1024              // k_select threads (16 waves)
#define CH 9                 // ceil(NALL/TS)

// ---------------- Kernel 1: IoU matching (cross-mul argmax, 2 rois/thread) ----
// Thread r handles rois r and r+4160 (both coalesced), so each gt's
// ds_read_b128 is amortized over 2 pairs and the gt area is recomputed in
// VALU (3 ops shared by both rois) instead of a second LDS read -- the
// CU-shared LDS pipe drops from ~18 to ~6 cyc/pair. Argmax never divides:
// iou_j > iou_b  <=>  inter_j * uc_b > inter_b * uc_j  (uc = max(uni,1e-8) > 0).
// 4 ILP chains per roi over ascending j-ranges; strict > keeps first-max.
// The >=0.5 / >=0.0 code comes from ONE contract-off IEEE division per roi
// on the winner (bit-exact thresholds; validated rounds 8-9). Masked-box
// slow path preserves full reference semantics.
__global__ __launch_bounds__(128) void k_match(
    const float* __restrict__ rois,   // B,NROIS,4
    const float* __restrict__ gt,     // B,NGT,4
    const float* __restrict__ noise,  // B,NALL,2
    int* __restrict__ mword)          // B*NALL : col | code<<7 | bin<<9
{
  __shared__ float4 sg[NGT];
  __shared__ float sab[NGT];           // areas (slow path only)
  __shared__ unsigned long long smask[2];

  const int b = blockIdx.y;
  const int tid = threadIdx.x;
  const float4* gt4 = reinterpret_cast<const float4*>(gt) + (size_t)b * NGT;
  const float4* rois4 = reinterpret_cast<const float4*>(rois) + (size_t)b * NROIS;

  // prologue: stage gt boxes + areas + mask ballot (tid covers all 128 gts)
  float4 g0 = gt4[tid];
  sg[tid] = g0;
  sab[tid] = (g0.z - g0.x) * (g0.w - g0.y);
  const bool mflag = (g0.x == -1.0f) && (g0.y == -1.0f) && (g0.z == -1.0f) && (g0.w == -1.0f);
  const unsigned long long mb = __ballot(mflag);
  if ((tid & 63) == 0) smask[tid >> 6] = mb;
  __syncthreads();
  const bool anymask = (smask[0] | smask[1]) != 0ULL;

  const int r = blockIdx.x * 128 + tid;   // 33*128 = 4224 >= 4160
  const bool act = (r < NHALF);
  const int i1 = r;                       // < 4160 -> always in rois
  const int i2 = r + NHALF;               // 4160..8319

  float4 A1 = act ? rois4[i1] : rois4[0];
  float4 A2 = act ? ((i2 < NROIS) ? rois4[i2] : sg[i2 - NROIS]) : rois4[0];
  const float aar1 = (A1.z - A1.x) * (A1.w - A1.y);
  const float aar2 = (A2.z - A2.x) * (A2.w - A2.y);
  const bool ma1 = act && (A1.x == -1.0f) && (A1.y == -1.0f) && (A1.z == -1.0f) && (A1.w == -1.0f);
  const bool ma2 = act && (A2.x == -1.0f) && (A2.y == -1.0f) && (A2.z == -1.0f) && (A2.w == -1.0f);

  int cc1, cc2;      // argmax cols
  int code1, code2;  // 3=pos, 1=neg, 0=ignore

  if (!anymask && __ballot(ma1 || ma2) == 0ULL) {
    // ---- fast path: cross-multiplication ordering, 8 independent chains ----
    float bi1[4], bu1[4], bi2[4], bu2[4];
    int bc1[4], bc2[4];
    #pragma unroll
    for (int c = 0; c < 4; ++c) {
      bi1[c] = 0.0f; bu1[c] = 1.0f; bc1[c] = c * 32;
      bi2[c] = 0.0f; bu2[c] = 1.0f; bc2[c] = c * 32;
    }

    #pragma unroll 4
    for (int jj = 0; jj < 32; ++jj) {
      #pragma unroll
      for (int c = 0; c < 4; ++c) {
        const int j = c * 32 + jj;
        const float4 g = sg[j];                      // one b128 for 2 pairs
        const float ab = (g.z - g.x) * (g.w - g.y);  // shared, VALU
        // roi 1
        {
          float iy = fmaxf(fminf(A1.z, g.z) - fmaxf(A1.x, g.x), 0.0f);
          float ix = fmaxf(fminf(A1.w, g.w) - fmaxf(A1.y, g.y), 0.0f);
          float inter = iy * ix;
          float uc = fmaxf((aar1 + ab) - inter, 1e-8f);
          const bool win = (inter * bu1[c]) > (bi1[c] * uc);
          bi1[c] = win ? inter : bi1[c];
          bu1[c] = win ? uc : bu1[c];
          bc1[c] = win ? j : bc1[c];
        }
        // roi 2
        {
          float iy = fmaxf(fminf(A2.z, g.z) - fmaxf(A2.x, g.x), 0.0f);
          float ix = fmaxf(fminf(A2.w, g.w) - fmaxf(A2.y, g.y), 0.0f);
          float inter = iy * ix;
          float uc = fmaxf((aar2 + ab) - inter, 1e-8f);
          const bool win = (inter * bu2[c]) > (bi2[c] * uc);
          bi2[c] = win ? inter : bi2[c];
          bu2[c] = win ? uc : bu2[c];
          bc2[c] = win ? j : bc2[c];
        }
      }
    }
    // merge ascending chains; strict > keeps lowest index among equals
    float qi = bi1[0], qu = bu1[0];
    cc1 = bc1[0];
    #pragma unroll
    for (int c = 1; c < 4; ++c) {
      const bool win = (bi1[c] * qu) > (qi * bu1[c]);
      qi = win ? bi1[c] : qi; qu = win ? bu1[c] : qu; cc1 = win ? bc1[c] : cc1;
    }
    qi = bi2[0]; qu = bu2[0]; cc2 = bc2[0];
    #pragma unroll
    for (int c = 1; c < 4; ++c) {
      const bool win = (bi2[c] * qu) > (qi * bu2[c]);
      qi = win ? bi2[c] : qi; qu = win ? bu2[c] : qu; cc2 = win ? bc2[c] : cc2;
    }
    // exact thresholds: one contract-off IEEE div per roi
    {
      #pragma clang fp contract(off)
      {
        const float4 g = sg[cc1];
        float iy = fmaxf(fminf(A1.z, g.z) - fmaxf(A1.x, g.x), 0.0f);
        float ix = fmaxf(fminf(A1.w, g.w) - fmaxf(A1.y, g.y), 0.0f);
        float inter = iy * ix;
        float ab = (g.z - g.x) * (g.w - g.y);
        float uni = (aar1 + ab) - inter;
        float bb = inter / fmaxf(uni, 1e-8f);
        code1 = (bb >= 0.5f) ? 3 : ((bb >= 0.0f) ? 1 : 0);
      }
      {
        const float4 g = sg[cc2];
        float iy = fmaxf(fminf(A2.z, g.z) - fmaxf(A2.x, g.x), 0.0f);
        float ix = fmaxf(fminf(A2.w, g.w) - fmaxf(A2.y, g.y), 0.0f);
        float inter = iy * ix;
        float ab = (g.z - g.x) * (g.w - g.y);
        float uni = (aar2 + ab) - inter;
        float bb = inter / fmaxf(uni, 1e-8f);
        code2 = (bb >= 0.5f) ? 3 : ((bb >= 0.0f) ? 1 : 0);
      }
    }
  } else {
    // ---- slow path (masked boxes; never taken for this data) ----
    #pragma clang fp contract(off)
    float bb1 = -3.0e38f, bb2 = -3.0e38f;
    cc1 = 0; cc2 = 0;
    for (int j = 0; j < NGT; ++j) {
      float4 gg = sg[j];
      const bool mj = (gg.x == -1.0f) && (gg.y == -1.0f) && (gg.z == -1.0f) && (gg.w == -1.0f);
      {
        float iy = fmaxf(fminf(A1.z, gg.z) - fmaxf(A1.x, gg.x), 0.0f);
        float ix = fmaxf(fminf(A1.w, gg.w) - fmaxf(A1.y, gg.y), 0.0f);
        float inter = iy * ix;
        float uni = (aar1 + sab[j]) - inter;
        float iou = inter / fmaxf(uni, 1e-8f);
        if (ma1 || mj) iou = -1.0f;
        if (iou > bb1) { bb1 = iou; cc1 = j; }
      }
      {
        float iy = fmaxf(fminf(A2.z, gg.z) - fmaxf(A2.x, gg.x), 0.0f);
        float ix = fmaxf(fminf(A2.w, gg.w) - fmaxf(A2.y, gg.y), 0.0f);
        float inter = iy * ix;
        float uni = (aar2 + sab[j]) - inter;
        float iou = inter / fmaxf(uni, 1e-8f);
        if (ma2 || mj) iou = -1.0f;
        if (iou > bb2) { bb2 = iou; cc2 = j; }
      }
    }
    code1 = (bb1 >= 0.5f) ? 3 : ((bb1 >= 0.0f) ? 1 : 0);
    code2 = (bb2 >= 0.5f) ? 3 : ((bb2 >= 0.0f) ? 1 : 0);
  }

  if (act) {
    {
      float2 nz = reinterpret_cast<const float2*>(noise)[(size_t)b * NALL + i1];
      float v = (code1 == 3) ? nz.x : nz.y;
      int bin = (int)(v * 1024.0f);
      bin = bin < 0 ? 0 : (bin > 1023 ? 1023 : bin);
      mword[(size_t)b * NALL + i1] = cc1 | (code1 << 7) | (bin << 9);
    }
    {
      float2 nz = reinterpret_cast<const float2*>(noise)[(size_t)b * NALL + i2];
      float v = (code2 == 3) ? nz.x : nz.y;
      int bin = (int)(v * 1024.0f);
      bin = bin < 0 ? 0 : (bin > 1023 ? 1023 : bin);
      mword[(size_t)b * NALL + i2] = cc2 | (code2 << 7) | (bin << 9);
    }
  }
}

// ---------------- shfl-based block inclusive scan (TS=1024, 16 waves) -------
__device__ __forceinline__ int block_incl_scan(int v, int tid, int* wsum) {
  __syncthreads();  // protect wsum reuse across consecutive calls
  int s = v;
  #pragma unroll
  for (int off = 1; off < 64; off <<= 1) {
    int u = __shfl_up(s, off);
    if ((tid & 63) >= off) s += u;
  }
  const int wid = tid >> 6;
  if ((tid & 63) == 63) wsum[wid] = s;
  __syncthreads();
  if (wid == 0) {
    const int lane = tid & 63;
    int w = (lane < (TS >> 6)) ? wsum[lane] : 0;
    #pragma unroll
    for (int off = 1; off < (TS >> 6); off <<= 1) {
      int u = __shfl_up(w, off);
      if (lane >= off) w += u;
    }
    if (lane < (TS >> 6)) wsum[lane] = w;
  }
  __syncthreads();
  return s + (wid ? wsum[wid - 1] : 0);
}

// ---------------- Kernel 2: balanced sampling + ordering + gather ------------
__global__ __launch_bounds__(TS) void k_select(
    const int* __restrict__ mword,
    const float* __restrict__ noise,  // B,NALL,2
    const float* __restrict__ rois,
    const float* __restrict__ gt,
    const float* __restrict__ gtcls,  // B,NGT,1
    float* __restrict__ out)
{
  #pragma clang fp contract(off)
  const int b = blockIdx.x;
  const int tid = threadIdx.x;

  __shared__ int hist[1024];            // packed pos|neg<<16
  __shared__ int wsum[TS >> 6];
  __shared__ int s_total;               // packed totals
  __shared__ float bval[2][BCAP];
  __shared__ int bidx_[2][BCAP];
  __shared__ int bcnt[2];
  __shared__ int s_bstar[2], s_need[2];
  __shared__ unsigned char ind[NALL];
  __shared__ unsigned short sorder[NSAMP];

  int ew[CH];     // packed word; bit7 set => candidate

  hist[tid] = 0;
  if (tid < 2) bcnt[tid] = 0;

  // ---- pass 1: one int load per element; histogram + ind init ----
  #pragma unroll
  for (int k = 0; k < CH; ++k) {
    const int i = tid + k * TS;
    int w = 0;
    if (i < NALL) {
      ind[i] = 0;
      w = mword[(size_t)b * NALL + i];
    }
    ew[k] = w;
  }
  __syncthreads();
  #pragma unroll
  for (int k = 0; k < CH; ++k) {
    const int w = ew[k];
    if (w & 0x80) atomicAdd(&hist[w >> 9], (w & 0x100) ? 1 : (1 << 16));
  }
  __syncthreads();

  // ---- packed suffix scan, one bin per thread ----
  const int c = hist[tid];
  const int incl = block_incl_scan(c, tid, wsum);
  if (tid == TS - 1) s_total = incl;
  __syncthreads();
  const int total = s_total;

  #pragma unroll
  for (int p = 0; p < 2; ++p) {
    const int want = p ? KNEG : KPOS;
    const int sh = p ? 16 : 0;
    const int tot = (total >> sh) & 0xFFFF;
    if (tot >= want) {                              // !selall
      const int inc = (incl >> sh) & 0xFFFF;
      const int cp = (c >> sh) & 0xFFFF;
      const int above = tot - inc;                  // sum of bins > tid
      if (above < want && above + cp >= want) {     // unique boundary thread
        s_bstar[p] = tid; s_need[p] = want - above;
      }
    }
  }
  __syncthreads();

  const bool selall0 = ((total & 0xFFFF) < KPOS);
  const bool selall1 = (((total >> 16) & 0xFFFF) < KNEG);

  // ---- mark: bins above boundary selected; boundary bins collected ----
  #pragma unroll
  for (int k = 0; k < CH; ++k) {
    const int w = ew[k];
    if (w & 0x80) {
      const int i = tid + k * TS;
      const int p = (w & 0x100) ? 0 : 1;
      const bool selall = p ? selall1 : selall0;
      const int bin = w >> 9;
      if (selall || bin > s_bstar[p]) {
        ind[i] = 1;
      } else if (bin == s_bstar[p]) {
        int pos = atomicAdd(&bcnt[p], 1);
        if (pos < BCAP) {
          bval[p][pos] = noise[((size_t)b * NALL + i) * 2 + p];  // rare reload
          bidx_[p][pos] = i;
        }
      }
    }
  }
  __syncthreads();

  // ---- boundary-bin exact top-k via parallel rank (value desc, idx asc) ----
  #pragma unroll
  for (int p = 0; p < 2; ++p) {
    const bool selall = p ? selall1 : selall0;
    if (selall) continue;
    int cnt = bcnt[p]; if (cnt > BCAP) cnt = BCAP;
    const int need = s_need[p];
    for (int x = tid; x < cnt; x += TS) {
      const float v = bval[p][x];
      const int id = bidx_[p][x];
      int rank = 0;
      for (int y = 0; y < cnt; ++y) {
        const float vy = bval[p][y];
        const int iy2 = bidx_[p][y];
        rank += (vy > v) || (vy == v && iy2 < id);
      }
      if (rank < need) ind[id] = 1;
    }
  }
  __syncthreads();

  // ---- ordering: ones ascending then zeros ascending (top_k of 0/1) ----
  const int start = tid * CH;
  const int end = (start + CH < NALL) ? (start + CH) : NALL;
  int cnt1 = 0;
  for (int i = start; i < end; ++i) cnt1 += ind[i];
  const int incl1 = block_incl_scan(cnt1, tid, wsum);
  if (tid == TS - 1) s_total = incl1;
  __syncthreads();
  const int K1 = s_total;
  int ones_before = incl1 - cnt1;
  const int nzero = NSAMP - K1;
  for (int i = start; i < end; ++i) {
    if (ind[i]) {
      sorder[ones_before] = (unsigned short)i;
      ones_before++;
    } else {
      const int zrank = i - ones_before;
      if (zrank < nzero) sorder[K1 + zrank] = (unsigned short)i;
    }
  }
  __syncthreads();

  // ---- fused gather + encode + write (one sample per thread) ----
  if (tid < NSAMP) {
    const int s = tid;
    const int idx = sorder[s];
    const size_t t = (size_t)b * NSAMP + s;

    float4 A = (idx < NROIS)
      ? reinterpret_cast<const float4*>(rois)[(size_t)b * NROIS + idx]
      : reinterpret_cast<const float4*>(gt)[(size_t)b * NGT + (idx - NROIS)];

    const int w = mword[(size_t)b * NALL + idx];
    const int col = w & 0x7F;
    const bool pos = (((w >> 7) & 3) == 3);

    float e0 = 0.f, e1 = 0.f, e2 = 0.f, e3 = 0.f, cls = 0.f;
    if (pos) {
      float4 G = reinterpret_cast<const float4*>(gt)[(size_t)b * NGT + col];
      float ah = A.z - A.x, aw = A.w - A.y;
      float acy = A.x + 0.5f * ah, acx = A.y + 0.5f * aw;
      float bh = G.z - G.x, bw = G.w - G.y;
      float bcy = G.x + 0.5f * bh, bcx = G.y + 0.5f * bw;
      e0 = ((bcy - acy) / ah) / 0.1f;
      e1 = ((bcx - acx) / aw) / 0.1f;
      e2 = logf(bh / ah) / 0.2f;
      e3 = logf(bw / aw) / 0.2f;
      cls = gtcls[(size_t)b * NGT + col];
    }

    float* o_rois = out;                           // NB*NSAMP*4
    float* o_enc  = out + (size_t)NB * NSAMP * 4;  // NB*NSAMP*4
    float* o_bw   = out + (size_t)NB * NSAMP * 8;
    float* o_cls  = o_bw + (size_t)NB * NSAMP;
    float* o_cw   = o_cls + (size_t)NB * NSAMP;

    reinterpret_cast<float4*>(o_rois)[t] = A;
    float4 E; E.x = e0; E.y = e1; E.z = e2; E.w = e3;
    reinterpret_cast<float4*>(o_enc)[t] = E;
    o_bw[t]  = pos ? 1.0f : 0.0f;
    o_cls[t] = cls;
    o_cw[t]  = (s < K1) ? 1.0f : 0.0f;
  }
}

extern "C" void kernel_launch(void* const* d_in, const int* in_sizes, int n_in,
                              void* d_out, int out_size, void* d_ws, size_t ws_size,
                              hipStream_t stream) {
  const float* rois  = (const float*)d_in[0];
  const float* gt    = (const float*)d_in[1];
  const float* gtcls = (const float*)d_in[2];
  const float* noise = (const float*)d_in[3];
  float* out = (float*)d_out;

  int* mword = (int*)d_ws;  // NB*NALL ints

  dim3 g1((NHALF + 127) / 128, NB);  // (33, 32), 2 rois/thread
  k_match<<<g1, 128, 0, stream>>>(rois, gt, noise, mword);
  k_select<<<NB, TS, 0, stream>>>(mword, noise, rois, gt, gtcls, out);
}

// Round 11
// 39.271 us; speedup vs baseline: 1.1052x; 1.1052x over previous
//
#include <hip/hip_runtime.h>
#include <cstdint>

#define NB 32
#define NROIS 8192
#define NGT 128
#define NALL (NROIS + NGT)   // 8320
#define NSAMP 512
#define KPOS 128
#define KNEG 384
#define BCAP 1024
#define TS 1024              // k_select threads (16 waves)
#define CH 9                 // ceil(NALL/TS)

// ---------------- Kernel 1: IoU matching (cross-mul argmax, gt-split x2) ------
// 256 thr/block, grid (65,32): block owns 128 rois; threads (r, half) with
// half in {0,1} each scan 64 gts for roi r -> 8320 waves (~full CU residency,
// 2x round 9). Argmax never divides: iou_j > iou_b <=> inter_j*uc_b >
// inter_b*uc_j (uc = max(uni,1e-8) > 0). 4 ILP chains per thread over
// ascending 16-gt ranges; strict > keeps first-max; chains merged ascending;
// halves merged via LDS with half0 (lower j) winning ties. One contract-off
// IEEE div per roi on the winner gives bit-exact >=0.5/>=0.0 codes
// (validated rounds 8-10). Fast/slow is BLOCK-uniform (LDS flag) so the
// merge barrier is legal; slow path keeps full reference semantics.
__global__ __launch_bounds__(256) void k_match(
    const float* __restrict__ rois,   // B,NROIS,4
    const float* __restrict__ gt,     // B,NGT,4
    const float* __restrict__ noise,  // B,NALL,2
    int* __restrict__ mword)          // B*NALL : col | code<<7 | bin<<9
{
  __shared__ float4 sg[NGT];
  __shared__ float sab[NGT];           // areas (slow path only)
  __shared__ int s_any;
  __shared__ float mbi[128], mbu[128];
  __shared__ int mbc[128];

  const int b = blockIdx.y;
  const int tid = threadIdx.x;
  const int r = tid & 127;
  const int half = tid >> 7;
  const float4* gt4 = reinterpret_cast<const float4*>(gt) + (size_t)b * NGT;
  const float4* rois4 = reinterpret_cast<const float4*>(rois) + (size_t)b * NROIS;

  if (tid == 0) s_any = 0;
  bool mflag = false;
  if (tid < NGT) {
    float4 g0 = gt4[tid];
    sg[tid] = g0;
    sab[tid] = (g0.z - g0.x) * (g0.w - g0.y);
    mflag = (g0.x == -1.0f) && (g0.y == -1.0f) && (g0.z == -1.0f) && (g0.w == -1.0f);
  }

  const int i = blockIdx.x * 128 + r;   // 65*128 == NALL exactly
  float4 A = (blockIdx.x < 64) ? rois4[i] : gt4[r];
  const float aar = (A.z - A.x) * (A.w - A.y);
  const bool ma = (A.x == -1.0f) && (A.y == -1.0f) && (A.z == -1.0f) && (A.w == -1.0f);

  __syncthreads();                       // s_any init + sg staged
  if (mflag || ma) atomicOr(&s_any, 1);
  __syncthreads();                       // s_any final (block-uniform)

  if (s_any == 0) {
    // ---- fast path: cross-mul ordering, 4 chains over this half's 64 gts ----
    const int jb = half * 64;
    float bi[4], bu[4];
    int bc[4];
    #pragma unroll
    for (int c = 0; c < 4; ++c) { bi[c] = 0.0f; bu[c] = 1.0f; bc[c] = jb + c * 16; }

    #pragma unroll 4
    for (int jj = 0; jj < 16; ++jj) {
      #pragma unroll
      for (int c = 0; c < 4; ++c) {
        const int j = jb + c * 16 + jj;
        const float4 g = sg[j];
        const float ab = (g.z - g.x) * (g.w - g.y);   // VALU, no LDS read
        float iy = fmaxf(fminf(A.z, g.z) - fmaxf(A.x, g.x), 0.0f);
        float ix = fmaxf(fminf(A.w, g.w) - fmaxf(A.y, g.y), 0.0f);
        float inter = iy * ix;
        float uc = fmaxf((aar + ab) - inter, 1e-8f);
        const bool win = (inter * bu[c]) > (bi[c] * uc);
        bi[c] = win ? inter : bi[c];
        bu[c] = win ? uc : bu[c];
        bc[c] = win ? j : bc[c];
      }
    }
    // merge 4 ascending chains; strict > keeps lowest index among equals
    float qi = bi[0], qu = bu[0];
    int qc = bc[0];
    #pragma unroll
    for (int c = 1; c < 4; ++c) {
      const bool win = (bi[c] * qu) > (qi * bu[c]);
      qi = win ? bi[c] : qi; qu = win ? bu[c] : qu; qc = win ? bc[c] : qc;
    }
    // merge halves: half1 publishes, half0 wins ties (lower j)
    if (half) { mbi[r] = qi; mbu[r] = qu; mbc[r] = qc; }
    __syncthreads();
    if (!half) {
      const float oi = mbi[r], ou = mbu[r];
      const int oc = mbc[r];
      const bool win = (oi * qu) > (qi * ou);
      qi = win ? oi : qi; qu = win ? ou : qu; qc = win ? oc : qc;

      int code;
      {
        #pragma clang fp contract(off)
        const float4 g = sg[qc];
        float iy = fmaxf(fminf(A.z, g.z) - fmaxf(A.x, g.x), 0.0f);
        float ix = fmaxf(fminf(A.w, g.w) - fmaxf(A.y, g.y), 0.0f);
        float inter = iy * ix;
        float ab = (g.z - g.x) * (g.w - g.y);
        float uni = (aar + ab) - inter;
        float bb = inter / fmaxf(uni, 1e-8f);   // IEEE-exact
        code = (bb >= 0.5f) ? 3 : ((bb >= 0.0f) ? 1 : 0);
      }
      float2 nz = reinterpret_cast<const float2*>(noise)[(size_t)b * NALL + i];
      float v = (code == 3) ? nz.x : nz.y;
      int bin = (int)(v * 1024.0f);
      bin = bin < 0 ? 0 : (bin > 1023 ? 1023 : bin);
      mword[(size_t)b * NALL + i] = qc | (code << 7) | (bin << 9);
    }
  } else {
    // ---- slow path (masked boxes; never taken for this data) ----
    if (!half) {
      #pragma clang fp contract(off)
      float bb = -3.0e38f;
      int cc = 0;
      for (int j = 0; j < NGT; ++j) {
        float4 gg = sg[j];
        const bool mj = (gg.x == -1.0f) && (gg.y == -1.0f) && (gg.z == -1.0f) && (gg.w == -1.0f);
        float iy = fmaxf(fminf(A.z, gg.z) - fmaxf(A.x, gg.x), 0.0f);
        float ix = fmaxf(fminf(A.w, gg.w) - fmaxf(A.y, gg.y), 0.0f);
        float inter = iy * ix;
        float uni = (aar + sab[j]) - inter;
        float iou = inter / fmaxf(uni, 1e-8f);
        if (ma || mj) iou = -1.0f;
        if (iou > bb) { bb = iou; cc = j; }   // ascending strict > = first-max
      }
      int code = (bb >= 0.5f) ? 3 : ((bb >= 0.0f) ? 1 : 0);
      float2 nz = reinterpret_cast<const float2*>(noise)[(size_t)b * NALL + i];
      float v = (code == 3) ? nz.x : nz.y;
      int bin = (int)(v * 1024.0f);
      bin = bin < 0 ? 0 : (bin > 1023 ? 1023 : bin);
      mword[(size_t)b * NALL + i] = cc | (code << 7) | (bin << 9);
    }
  }
}

// ---------------- shfl-based block inclusive scan (TS=1024, 16 waves) -------
__device__ __forceinline__ int block_incl_scan(int v, int tid, int* wsum) {
  __syncthreads();  // protect wsum reuse across consecutive calls
  int s = v;
  #pragma unroll
  for (int off = 1; off < 64; off <<= 1) {
    int u = __shfl_up(s, off);
    if ((tid & 63) >= off) s += u;
  }
  const int wid = tid >> 6;
  if ((tid & 63) == 63) wsum[wid] = s;
  __syncthreads();
  if (wid == 0) {
    const int lane = tid & 63;
    int w = (lane < (TS >> 6)) ? wsum[lane] : 0;
    #pragma unroll
    for (int off = 1; off < (TS >> 6); off <<= 1) {
      int u = __shfl_up(w, off);
      if (lane >= off) w += u;
    }
    if (lane < (TS >> 6)) wsum[lane] = w;
  }
  __syncthreads();
  return s + (wid ? wsum[wid - 1] : 0);
}

// ---------------- Kernel 2: balanced sampling + ordering + gather ------------
__global__ __launch_bounds__(TS) void k_select(
    const int* __restrict__ mword,
    const float* __restrict__ noise,  // B,NALL,2
    const float* __restrict__ rois,
    const float* __restrict__ gt,
    const float* __restrict__ gtcls,  // B,NGT,1
    float* __restrict__ out)
{
  #pragma clang fp contract(off)
  const int b = blockIdx.x;
  const int tid = threadIdx.x;

  __shared__ int hist[1024];            // packed pos|neg<<16
  __shared__ int wsum[TS >> 6];
  __shared__ int s_total;               // packed totals
  __shared__ float bval[2][BCAP];
  __shared__ int bidx_[2][BCAP];
  __shared__ int bcnt[2];
  __shared__ int s_bstar[2], s_need[2];
  __shared__ unsigned char ind[NALL];
  __shared__ unsigned short sorder[NSAMP];

  int ew[CH];     // packed word; bit7 set => candidate

  hist[tid] = 0;
  if (tid < 2) bcnt[tid] = 0;

  // ---- pass 1: one int load per element; histogram + ind init ----
  #pragma unroll
  for (int k = 0; k < CH; ++k) {
    const int i = tid + k * TS;
    int w = 0;
    if (i < NALL) {
      ind[i] = 0;
      w = mword[(size_t)b * NALL + i];
    }
    ew[k] = w;
  }
  __syncthreads();
  #pragma unroll
  for (int k = 0; k < CH; ++k) {
    const int w = ew[k];
    if (w & 0x80) atomicAdd(&hist[w >> 9], (w & 0x100) ? 1 : (1 << 16));
  }
  __syncthreads();

  // ---- packed suffix scan, one bin per thread ----
  const int c = hist[tid];
  const int incl = block_incl_scan(c, tid, wsum);
  if (tid == TS - 1) s_total = incl;
  __syncthreads();
  const int total = s_total;

  #pragma unroll
  for (int p = 0; p < 2; ++p) {
    const int want = p ? KNEG : KPOS;
    const int sh = p ? 16 : 0;
    const int tot = (total >> sh) & 0xFFFF;
    if (tot >= want) {                              // !selall
      const int inc = (incl >> sh) & 0xFFFF;
      const int cp = (c >> sh) & 0xFFFF;
      const int above = tot - inc;                  // sum of bins > tid
      if (above < want && above + cp >= want) {     // unique boundary thread
        s_bstar[p] = tid; s_need[p] = want - above;
      }
    }
  }
  __syncthreads();

  const bool selall0 = ((total & 0xFFFF) < KPOS);
  const bool selall1 = (((total >> 16) & 0xFFFF) < KNEG);

  // ---- mark: bins above boundary selected; boundary bins collected ----
  #pragma unroll
  for (int k = 0; k < CH; ++k) {
    const int w = ew[k];
    if (w & 0x80) {
      const int i = tid + k * TS;
      const int p = (w & 0x100) ? 0 : 1;
      const bool selall = p ? selall1 : selall0;
      const int bin = w >> 9;
      if (selall || bin > s_bstar[p]) {
        ind[i] = 1;
      } else if (bin == s_bstar[p]) {
        int pos = atomicAdd(&bcnt[p], 1);
        if (pos < BCAP) {
          bval[p][pos] = noise[((size_t)b * NALL + i) * 2 + p];  // rare reload
          bidx_[p][pos] = i;
        }
      }
    }
  }
  __syncthreads();

  // ---- boundary-bin exact top-k via parallel rank (value desc, idx asc) ----
  #pragma unroll
  for (int p = 0; p < 2; ++p) {
    const bool selall = p ? selall1 : selall0;
    if (selall) continue;
    int cnt = bcnt[p]; if (cnt > BCAP) cnt = BCAP;
    const int need = s_need[p];
    for (int x = tid; x < cnt; x += TS) {
      const float v = bval[p][x];
      const int id = bidx_[p][x];
      int rank = 0;
      for (int y = 0; y < cnt; ++y) {
        const float vy = bval[p][y];
        const int iy2 = bidx_[p][y];
        rank += (vy > v) || (vy == v && iy2 < id);
      }
      if (rank < need) ind[id] = 1;
    }
  }
  __syncthreads();

  // ---- ordering: ones ascending then zeros ascending (top_k of 0/1) ----
  const int start = tid * CH;
  const int end = (start + CH < NALL) ? (start + CH) : NALL;
  int cnt1 = 0;
  for (int i = start; i < end; ++i) cnt1 += ind[i];
  const int incl1 = block_incl_scan(cnt1, tid, wsum);
  if (tid == TS - 1) s_total = incl1;
  __syncthreads();
  const int K1 = s_total;
  int ones_before = incl1 - cnt1;
  const int nzero = NSAMP - K1;
  for (int i = start; i < end; ++i) {
    if (ind[i]) {
      sorder[ones_before] = (unsigned short)i;
      ones_before++;
    } else {
      const int zrank = i - ones_before;
      if (zrank < nzero) sorder[K1 + zrank] = (unsigned short)i;
    }
  }
  __syncthreads();

  // ---- fused gather + encode + write (one sample per thread) ----
  if (tid < NSAMP) {
    const int s = tid;
    const int idx = sorder[s];
    const size_t t = (size_t)b * NSAMP + s;

    float4 A = (idx < NROIS)
      ? reinterpret_cast<const float4*>(rois)[(size_t)b * NROIS + idx]
      : reinterpret_cast<const float4*>(gt)[(size_t)b * NGT + (idx - NROIS)];

    const int w = mword[(size_t)b * NALL + idx];
    const int col = w & 0x7F;
    const bool pos = (((w >> 7) & 3) == 3);

    float e0 = 0.f, e1 = 0.f, e2 = 0.f, e3 = 0.f, cls = 0.f;
    if (pos) {
      float4 G = reinterpret_cast<const float4*>(gt)[(size_t)b * NGT + col];
      float ah = A.z - A.x, aw = A.w - A.y;
      float acy = A.x + 0.5f * ah, acx = A.y + 0.5f * aw;
      float bh = G.z - G.x, bw = G.w - G.y;
      float bcy = G.x + 0.5f * bh, bcx = G.y + 0.5f * bw;
      e0 = ((bcy - acy) / ah) / 0.1f;
      e1 = ((bcx - acx) / aw) / 0.1f;
      e2 = logf(bh / ah) / 0.2f;
      e3 = logf(bw / aw) / 0.2f;
      cls = gtcls[(size_t)b * NGT + col];
    }

    float* o_rois = out;                           // NB*NSAMP*4
    float* o_enc  = out + (size_t)NB * NSAMP * 4;  // NB*NSAMP*4
    float* o_bw   = out + (size_t)NB * NSAMP * 8;
    float* o_cls  = o_bw + (size_t)NB * NSAMP;
    float* o_cw   = o_cls + (size_t)NB * NSAMP;

    reinterpret_cast<float4*>(o_rois)[t] = A;
    float4 E; E.x = e0; E.y = e1; E.z = e2; E.w = e3;
    reinterpret_cast<float4*>(o_enc)[t] = E;
    o_bw[t]  = pos ? 1.0f : 0.0f;
    o_cls[t] = cls;
    o_cw[t]  = (s < K1) ? 1.0f : 0.0f;
  }
}

extern "C" void kernel_launch(void* const* d_in, const int* in_sizes, int n_in,
                              void* d_out, int out_size, void* d_ws, size_t ws_size,
                              hipStream_t stream) {
  const float* rois  = (const float*)d_in[0];
  const float* gt    = (const float*)d_in[1];
  const float* gtcls = (const float*)d_in[2];
  const float* noise = (const float*)d_in[3];
  float* out = (float*)d_out;

  int* mword = (int*)d_ws;  // NB*NALL ints

  dim3 g1(NALL / 128, NB);  // (65, 32) = 2080 blocks, 4 waves each (gt-split)
  k_match<<<g1, 256, 0, stream>>>(rois, gt, noise, mword);
  k_select<<<NB, TS, 0, stream>>>(mword, noise, rois, gt, gtcls, out);
}